// Round 8
// baseline (352.368 us; speedup 1.0000x reference)
//
#include <hip/hip_runtime.h>

#define H 768
#define FF 3072
#define NH 12
#define DH 64
#define SEQ 2048
#define MTOK 4096

typedef __attribute__((ext_vector_type(8))) short short8;
typedef __attribute__((ext_vector_type(4))) float f32x4;

__device__ __forceinline__ f32x4 mfma16(short8 a, short8 b, f32x4 c) {
  return __builtin_amdgcn_mfma_f32_16x16x32_bf16(a, b, c, 0, 0, 0);
}

__device__ __forceinline__ unsigned short f2bf(float f) {
  union { float f; unsigned int u; } c; c.f = f;
  unsigned int u = c.u;
  u += 0x7fffu + ((u >> 16) & 1u);  // round-to-nearest-even
  return (unsigned short)(u >> 16);
}
__device__ __forceinline__ float bf2f(unsigned short s) {
  union { unsigned int u; float f; } c; c.u = ((unsigned int)s) << 16;
  return c.f;
}
__device__ __forceinline__ unsigned int pk2bf(float lo, float hi) {
  return (unsigned int)f2bf(lo) | ((unsigned int)f2bf(hi) << 16);
}
// truncating bf16 pair pack: one v_perm_b32
__device__ __forceinline__ unsigned int pktrunc(float lo, float hi) {
  union { float f; unsigned int u; } a, b; a.f = hi; b.f = lo;
  return __builtin_amdgcn_perm(a.u, b.u, 0x07060302u);
}

// async global->LDS, 16B per lane; LDS dest = wave-uniform base + lane*16
__device__ __forceinline__ void gld16(const unsigned short* g, unsigned short* l) {
  __builtin_amdgcn_global_load_lds(
      (const __attribute__((address_space(1))) void*)g,
      (__attribute__((address_space(3))) void*)l, 16, 0, 0);
}

// ---------------- fused transpose+cast of all 6 weights: fp32 [K][N] -> bf16 [N][K] ----------------
__global__ __launch_bounds__(256) void transpose_all(
    const float* __restrict__ Wq, const float* __restrict__ Wk,
    const float* __restrict__ Wv, const float* __restrict__ Wo,
    const float* __restrict__ W1, const float* __restrict__ W2,
    unsigned short* __restrict__ WqkvT, unsigned short* __restrict__ WoT,
    unsigned short* __restrict__ W1T, unsigned short* __restrict__ W2T) {
  int bid = blockIdx.x;
  const float* in; unsigned short* out; int K, N, t0;
  if (bid < 1728) {
    K = 768; N = 768;
    if (bid < 576)       { in = Wq; out = WqkvT;                       t0 = bid; }
    else if (bid < 1152) { in = Wk; out = WqkvT + (size_t)768 * 768;   t0 = bid - 576; }
    else                 { in = Wv; out = WqkvT + (size_t)1536 * 768;  t0 = bid - 1152; }
  } else if (bid < 2304) { in = Wo; out = WoT; K = 768;  N = 768;  t0 = bid - 1728; }
  else if (bid < 4608)   { in = W1; out = W1T; K = 768;  N = 3072; t0 = bid - 2304; }
  else                   { in = W2; out = W2T; K = 3072; N = 768;  t0 = bid - 4608; }

  __shared__ float tile[32][33];
  int nb = N >> 5;
  int n0 = (t0 % nb) << 5;
  int k0 = (t0 / nb) << 5;
  int tx = threadIdx.x & 31, ty = threadIdx.x >> 5;
#pragma unroll
  for (int yy = 0; yy < 4; ++yy)
    tile[ty + yy * 8][tx] = in[(size_t)(k0 + ty + yy * 8) * N + n0 + tx];
  __syncthreads();
#pragma unroll
  for (int yy = 0; yy < 4; ++yy)
    out[(size_t)(n0 + ty + yy * 8) * K + k0 + tx] = f2bf(tile[tx][ty + yy * 8]);
}

// ---------------- LayerNorm fp32 [rows][768] -> bf16 ----------------
__global__ __launch_bounds__(256) void ln_kernel(const float* __restrict__ x,
                                                 const float* __restrict__ w,
                                                 const float* __restrict__ b,
                                                 unsigned short* __restrict__ out) {
  int row = blockIdx.x;
  int tid = threadIdx.x;
  const float* xr = x + (size_t)row * H;
  float v0 = xr[tid], v1 = xr[tid + 256], v2 = xr[tid + 512];
  float s = v0 + v1 + v2;
  float ss = v0 * v0 + v1 * v1 + v2 * v2;
#pragma unroll
  for (int off = 32; off > 0; off >>= 1) {
    s += __shfl_down(s, off);
    ss += __shfl_down(ss, off);
  }
  __shared__ float red[8];
  int wave = tid >> 6, lane = tid & 63;
  if (lane == 0) { red[wave] = s; red[4 + wave] = ss; }
  __syncthreads();
  s = red[0] + red[1] + red[2] + red[3];
  ss = red[4] + red[5] + red[6] + red[7];
  float mu = s * (1.0f / H);
  float var = ss * (1.0f / H) - mu * mu;
  float rs = rsqrtf(var + 1e-6f);
  unsigned short* orow = out + (size_t)row * H;
  orow[tid]       = f2bf((v0 - mu) * rs * w[tid]       + b[tid]);
  orow[tid + 256] = f2bf((v1 - mu) * rs * w[tid + 256] + b[tid + 256]);
  orow[tid + 512] = f2bf((v2 - mu) * rs * w[tid + 512] + b[tid + 512]);
}

// ---------------- GEMM m97-style: 128x128 tile, BK=32, global_load_lds w16 ----------------
enum { MODE_QKV = 0, MODE_RESID = 1, MODE_GELU = 2 };

template <int MODE>
__global__ __launch_bounds__(256) void gemm128(
    const unsigned short* __restrict__ A,   // [M,K] bf16
    const unsigned short* __restrict__ Bt,  // [N,K] bf16
    int M, int N, int K,
    const float* __restrict__ bias0,
    const float* __restrict__ bias1,
    const float* __restrict__ bias2,
    unsigned short* __restrict__ out_q,
    unsigned short* __restrict__ out_k,
    unsigned short* __restrict__ out_vT,
    unsigned short* __restrict__ out_bf)    // bf16 [M,N]
{
  const int nb = N >> 7;
  int n0 = (blockIdx.x % nb) << 7;
  int m0 = (blockIdx.x / nb) << 7;
  int tid = threadIdx.x;
  int wave = tid >> 6, lane = tid & 63;
  int quad = lane >> 4, l16 = lane & 15;
  int wm = (wave & 1) << 6;
  int wn = (wave >> 1) << 6;

  __shared__ __align__(16) unsigned short As[128 * 32];
  __shared__ __align__(16) unsigned short Bs[128 * 32];

  f32x4 acc[4][4];
#pragma unroll
  for (int i = 0; i < 4; ++i)
#pragma unroll
    for (int j = 0; j < 4; ++j) acc[i][j] = (f32x4){0.f, 0.f, 0.f, 0.f};

  int srow = lane >> 2;
  int scol = (lane & 3) << 3;
  const unsigned short* gA0 = A + (size_t)(m0 + wave * 32 + srow) * K + scol;
  const unsigned short* gA1 = gA0 + (size_t)16 * K;
  unsigned short* lA0 = &As[(wave * 32) * 32];
  unsigned short* lA1 = &As[(wave * 32 + 16) * 32];
  const unsigned short* gB0 = Bt + (size_t)(n0 + wave * 32 + srow) * K + scol;
  const unsigned short* gB1 = gB0 + (size_t)16 * K;
  unsigned short* lB0 = &Bs[(wave * 32) * 32];
  unsigned short* lB1 = &Bs[(wave * 32 + 16) * 32];

  for (int k0 = 0; k0 < K; k0 += 32) {
    gld16(gA0 + k0, lA0);
    gld16(gA1 + k0, lA1);
    gld16(gB0 + k0, lB0);
    gld16(gB1 + k0, lB1);
    __syncthreads();
    short8 af[4], bfr[4];
#pragma unroll
    for (int t = 0; t < 4; ++t)
      af[t] = *(const short8*)(&As[(wm + t * 16 + l16) * 32 + quad * 8]);
#pragma unroll
    for (int t = 0; t < 4; ++t)
      bfr[t] = *(const short8*)(&Bs[(wn + t * 16 + l16) * 32 + quad * 8]);
#pragma unroll
    for (int i = 0; i < 4; ++i)
#pragma unroll
      for (int j = 0; j < 4; ++j)
        acc[i][j] = mfma16(af[i], bfr[j], acc[i][j]);
    __syncthreads();
  }

#pragma unroll
  for (int mt = 0; mt < 4; ++mt)
#pragma unroll
    for (int nt = 0; nt < 4; ++nt) {
      f32x4 c = acc[mt][nt];
      int m = m0 + wm + mt * 16 + quad * 4;
      int n = n0 + wn + nt * 16 + l16;
      if (MODE == MODE_QKV) {
        int bb = m >> 11, sIdx = m & 2047;
        if (n < 768) {
          float bs = bias0[n];
          int hh = n >> 6, d = n & 63;
          unsigned short* dst = out_q + (((size_t)(bb * NH + hh)) * SEQ + sIdx) * DH + d;
#pragma unroll
          for (int r = 0; r < 4; ++r) dst[r * DH] = f2bf(c[r] + bs);
        } else if (n < 1536) {
          int nn = n - 768;
          float bs = bias1[nn];
          int hh = nn >> 6, d = nn & 63;
          unsigned short* dst = out_k + (((size_t)(bb * NH + hh)) * SEQ + sIdx) * DH + d;
#pragma unroll
          for (int r = 0; r < 4; ++r) dst[r * DH] = f2bf(c[r] + bs);
        } else {
          int nn = n - 1536;
          float bs = bias2[nn];
          int hh = nn >> 6, d = nn & 63;
          uint2 pk;
          pk.x = pk2bf(c[0] + bs, c[1] + bs);
          pk.y = pk2bf(c[2] + bs, c[3] + bs);
          *(uint2*)(out_vT + (((size_t)(bb * NH + hh)) * DH + d) * SEQ + sIdx) = pk;
        }
      } else {  // MODE_GELU
        float bs = bias0[n];
        unsigned short* op = out_bf + (size_t)m * N + n;
#pragma unroll
        for (int r = 0; r < 4; ++r) {
          float t = c[r] + bs;
          op[(size_t)r * N] = f2bf(0.5f * t * (1.0f + erff(t * 0.70710678118654752f)));
        }
      }
    }
}

// ---------------- GEMM 64x64 tile (for N=768 shapes): residual epilogue ----------------
__global__ __launch_bounds__(256) void gemm64r(
    const unsigned short* __restrict__ A,   // [M,K]
    const unsigned short* __restrict__ Bt,  // [N,K]
    int M, int N, int K,
    const float* __restrict__ bias0,
    const float* __restrict__ resid,        // fp32 [M,N]
    float* __restrict__ out_f)              // fp32 [M,N]
{
  const int nb = N >> 6;
  int n0 = (blockIdx.x % nb) << 6;
  int m0 = (blockIdx.x / nb) << 6;
  int tid = threadIdx.x;
  int wave = tid >> 6, lane = tid & 63;
  int quad = lane >> 4, l16 = lane & 15;
  int wm = (wave & 1) << 5;
  int wn = (wave >> 1) << 5;

  __shared__ __align__(16) unsigned short As[64 * 32];
  __shared__ __align__(16) unsigned short Bs[64 * 32];

  f32x4 acc[2][2];
#pragma unroll
  for (int i = 0; i < 2; ++i)
#pragma unroll
    for (int j = 0; j < 2; ++j) acc[i][j] = (f32x4){0.f, 0.f, 0.f, 0.f};

  int srow = lane >> 2;
  int scol = (lane & 3) << 3;
  const unsigned short* gA = A + (size_t)(m0 + wave * 16 + srow) * K + scol;
  unsigned short* lA = &As[(wave * 16) * 32];
  const unsigned short* gB = Bt + (size_t)(n0 + wave * 16 + srow) * K + scol;
  unsigned short* lB = &Bs[(wave * 16) * 32];

  for (int k0 = 0; k0 < K; k0 += 32) {
    gld16(gA + k0, lA);
    gld16(gB + k0, lB);
    __syncthreads();
    short8 af[2], bfr[2];
#pragma unroll
    for (int t = 0; t < 2; ++t)
      af[t] = *(const short8*)(&As[(wm + t * 16 + l16) * 32 + quad * 8]);
#pragma unroll
    for (int t = 0; t < 2; ++t)
      bfr[t] = *(const short8*)(&Bs[(wn + t * 16 + l16) * 32 + quad * 8]);
#pragma unroll
    for (int i = 0; i < 2; ++i)
#pragma unroll
      for (int j = 0; j < 2; ++j)
        acc[i][j] = mfma16(af[i], bfr[j], acc[i][j]);
    __syncthreads();
  }

#pragma unroll
  for (int mt = 0; mt < 2; ++mt)
#pragma unroll
    for (int nt = 0; nt < 2; ++nt) {
      f32x4 c = acc[mt][nt];
      int m = m0 + wm + mt * 16 + quad * 4;
      int n = n0 + wn + nt * 16 + l16;
      float bs = bias0[n];
      const float* rp = resid + (size_t)m * N + n;
      float* op = out_f + (size_t)m * N + n;
#pragma unroll
      for (int r = 0; r < 4; ++r) op[(size_t)r * N] = rp[(size_t)r * N] + c[r] + bs;
    }
}

// ---------------- flash attention v8: 8-way key split, 512 threads ----------------
// Block = 32 q-rows (2 tiles), 8 waves; wave w scans keys [w*256,(w+1)*256),
// 8 iters of 32 keys. Body = v7 (S^T trick, no max, bpermute P^T, 16B loads).
// 8 partials combined in LDS; 8 (t,dt) combos map 1:1 onto the 8 waves.
// bh-grouped bid mapping keeps each (b,h)'s K/V on one XCD's L2.
__global__ __launch_bounds__(512) void flash_attn_kernel(
    const unsigned short* __restrict__ q,   // [B,NH,S,DH]
    const unsigned short* __restrict__ k,   // [B,NH,S,DH]
    const unsigned short* __restrict__ vT,  // [B,NH,DH,S]
    unsigned short* __restrict__ ctx)       // [MTOK,H] bf16
{
  const float CEXP = 0.18033688011112042f;  // (1/8) * log2(e)
  int bh = blockIdx.x % 24;
  int qblk = blockIdx.x / 24;        // 64 q-blocks of 32
  int b = bh / NH, h = bh % NH;
  int tid = threadIdx.x;
  int wave = tid >> 6, lane = tid & 63;  // wave 0..7
  int quad = lane >> 4, l16 = lane & 15;
  int qbase = qblk << 5;

  const unsigned short* qp = q + ((size_t)bh * SEQ + qbase) * DH;
  const unsigned short* kp = k + (size_t)bh * SEQ * DH;
  const unsigned short* vp = vT + (size_t)bh * DH * SEQ;

  short8 qf00 = *(const short8*)(qp + l16 * DH + quad * 8);
  short8 qf01 = *(const short8*)(qp + l16 * DH + 32 + quad * 8);
  short8 qf10 = *(const short8*)(qp + (16 + l16) * DH + quad * 8);
  short8 qf11 = *(const short8*)(qp + (16 + l16) * DH + 32 + quad * 8);

  f32x4 oacc[2][4];
#pragma unroll
  for (int t = 0; t < 2; ++t)
#pragma unroll
    for (int dt = 0; dt < 4; ++dt) oacc[t][dt] = (f32x4){0.f, 0.f, 0.f, 0.f};
  float L[2] = {0.f, 0.f};   // per-lane partial (this quad's keys), q = l16

  int addrA = ((((2 * quad) & 3) << 4) + l16) << 2;
  int addrB = ((((2 * quad + 1) & 3) << 4) + l16) << 2;
  bool loquad = quad < 2;

  int keylo = wave << 8;     // 256 keys per wave
  for (int key0 = keylo; key0 < keylo + 256; key0 += 32) {
    const unsigned short* k0p = kp + (size_t)(key0 + l16) * DH;
    const unsigned short* k1p = kp + (size_t)(key0 + 16 + l16) * DH;
    short8 ka0 = *(const short8*)(k0p + quad * 8);
    short8 ka1 = *(const short8*)(k0p + 32 + quad * 8);
    short8 kb0 = *(const short8*)(k1p + quad * 8);
    short8 kb1 = *(const short8*)(k1p + 32 + quad * 8);
    short8 vf0 = *(const short8*)(vp + (size_t)(0 * 16 + l16) * SEQ + key0 + quad * 8);
    short8 vf1 = *(const short8*)(vp + (size_t)(1 * 16 + l16) * SEQ + key0 + quad * 8);
    short8 vf2 = *(const short8*)(vp + (size_t)(2 * 16 + l16) * SEQ + key0 + quad * 8);
    short8 vf3 = *(const short8*)(vp + (size_t)(3 * 16 + l16) * SEQ + key0 + quad * 8);

#pragma unroll
    for (int t = 0; t < 2; ++t) {
      short8 q0 = t ? qf10 : qf00;
      short8 q1 = t ? qf11 : qf01;
      f32x4 s0 = (f32x4){0.f, 0.f, 0.f, 0.f};
      f32x4 s1 = (f32x4){0.f, 0.f, 0.f, 0.f};
      s0 = mfma16(ka0, q0, s0);
      s0 = mfma16(ka1, q1, s0);
      s1 = mfma16(kb0, q0, s1);
      s1 = mfma16(kb1, q1, s1);

      f32x4 p0, p1;
#pragma unroll
      for (int r = 0; r < 4; ++r) {
        p0[r] = __builtin_amdgcn_exp2f(s0[r] * CEXP);
        p1[r] = __builtin_amdgcn_exp2f(s1[r] * CEXP);
      }
      L[t] += (p0[0] + p0[1]) + (p0[2] + p0[3]) + (p1[0] + p1[1]) + (p1[2] + p1[3]);

      int d00 = (int)pktrunc(p0[0], p0[1]);
      int d01 = (int)pktrunc(p0[2], p0[3]);
      int d10 = (int)pktrunc(p1[0], p1[1]);
      int d11 = (int)pktrunc(p1[2], p1[3]);

      int f0a = __builtin_amdgcn_ds_bpermute(addrA, d00);
      int f0b = __builtin_amdgcn_ds_bpermute(addrA, d10);
      int f1a = __builtin_amdgcn_ds_bpermute(addrA, d01);
      int f1b = __builtin_amdgcn_ds_bpermute(addrA, d11);
      int f2a = __builtin_amdgcn_ds_bpermute(addrB, d00);
      int f2b = __builtin_amdgcn_ds_bpermute(addrB, d10);
      int f3a = __builtin_amdgcn_ds_bpermute(addrB, d01);
      int f3b = __builtin_amdgcn_ds_bpermute(addrB, d11);
      union { short8 s; int i[4]; } pf;
      pf.i[0] = loquad ? f0a : f0b;
      pf.i[1] = loquad ? f1a : f1b;
      pf.i[2] = loquad ? f2a : f2b;
      pf.i[3] = loquad ? f3a : f3b;

      oacc[t][0] = mfma16(vf0, pf.s, oacc[t][0]);
      oacc[t][1] = mfma16(vf1, pf.s, oacc[t][1]);
      oacc[t][2] = mfma16(vf2, pf.s, oacc[t][2]);
      oacc[t][3] = mfma16(vf3, pf.s, oacc[t][3]);
    }
  }

  // reduce per-lane partial l over the 4 quads (keys) -> total for q=l16
#pragma unroll
  for (int t = 0; t < 2; ++t) {
    L[t] += __shfl_xor(L[t], 16);
    L[t] += __shfl_xor(L[t], 32);
  }

  // ---- combine partials across the 8 key-split waves ----
  __shared__ float lbuf[8][2][16];
  __shared__ uint2 obuf[8][2][4][64];

  if (lane < 16) {
    lbuf[wave][0][lane] = L[0];
    lbuf[wave][1][lane] = L[1];
  }
#pragma unroll
  for (int t = 0; t < 2; ++t)
#pragma unroll
    for (int dt = 0; dt < 4; ++dt) {
      uint2 pk;
      pk.x = pk2bf(oacc[t][dt][0], oacc[t][dt][1]);
      pk.y = pk2bf(oacc[t][dt][2], oacc[t][dt][3]);
      obuf[wave][t][dt][lane] = pk;
    }
  __syncthreads();

  {
    int t = wave >> 2, dt = wave & 3;   // 8 waves <-> 8 (t,dt) combos
    f32x4 sum = (f32x4){0.f, 0.f, 0.f, 0.f};
#pragma unroll
    for (int w = 0; w < 8; ++w) {
      uint2 pk = obuf[w][t][dt][lane];
      sum[0] += bf2f((unsigned short)(pk.x & 0xffff));
      sum[1] += bf2f((unsigned short)(pk.x >> 16));
      sum[2] += bf2f((unsigned short)(pk.y & 0xffff));
      sum[3] += bf2f((unsigned short)(pk.y >> 16));
    }
    float lstar = 0.f;
#pragma unroll
    for (int w = 0; w < 8; ++w) lstar += lbuf[w][t][l16];
    float rinv = 1.0f / lstar;
    uint2 res;
    res.x = pk2bf(sum[0] * rinv, sum[1] * rinv);
    res.y = pk2bf(sum[2] * rinv, sum[3] * rinv);
    unsigned short* crow = ctx + (size_t)(b * SEQ + qbase + t * 16 + l16) * H
                           + h * DH + dt * 16 + quad * 4;
    *(uint2*)crow = res;
  }
}

// ---------------- launch ----------------
extern "C" void kernel_launch(void* const* d_in, const int* in_sizes, int n_in,
                              void* d_out, int out_size, void* d_ws, size_t ws_size,
                              hipStream_t stream) {
  const float* latent = (const float*)d_in[0];
  const float* ln1_w = (const float*)d_in[1];
  const float* ln1_b = (const float*)d_in[2];
  const float* Wq = (const float*)d_in[3];
  const float* bq = (const float*)d_in[4];
  const float* Wk = (const float*)d_in[5];
  const float* bk = (const float*)d_in[6];
  const float* Wv = (const float*)d_in[7];
  const float* bv = (const float*)d_in[8];
  const float* Wo = (const float*)d_in[9];
  const float* bo = (const float*)d_in[10];
  const float* ln2_w = (const float*)d_in[11];
  const float* ln2_b = (const float*)d_in[12];
  const float* W1 = (const float*)d_in[13];
  const float* b1 = (const float*)d_in[14];
  const float* W2 = (const float*)d_in[15];
  const float* b2 = (const float*)d_in[16];
  float* out = (float*)d_out;

  char* ws = (char*)d_ws;
  unsigned short* WqkvT = (unsigned short*)ws; ws += (size_t)2304 * 768 * 2;
  unsigned short* WoT   = (unsigned short*)ws; ws += (size_t)768 * 768 * 2;
  unsigned short* W1T   = (unsigned short*)ws; ws += (size_t)3072 * 768 * 2;
  unsigned short* W2T   = (unsigned short*)ws; ws += (size_t)768 * 3072 * 2;
  unsigned short* nx    = (unsigned short*)ws; ws += (size_t)MTOK * H * 2;
  unsigned short* nx2   = (unsigned short*)ws; ws += (size_t)MTOK * H * 2;
  unsigned short* qb    = (unsigned short*)ws; ws += (size_t)MTOK * H * 2;
  unsigned short* kb    = (unsigned short*)ws; ws += (size_t)MTOK * H * 2;
  unsigned short* vTb   = (unsigned short*)ws; ws += (size_t)MTOK * H * 2;
  unsigned short* ctx   = (unsigned short*)ws; ws += (size_t)MTOK * H * 2;
  unsigned short* hbuf  = (unsigned short*)ws; ws += (size_t)MTOK * FF * 2;
  float* x1             = (float*)ws;          ws += (size_t)MTOK * H * 4;

  // all weights -> bf16 transposed, one launch
  transpose_all<<<6912, 256, 0, stream>>>(Wq, Wk, Wv, Wo, W1, W2,
                                          WqkvT, WoT, W1T, W2T);

  // LN1
  ln_kernel<<<MTOK, 256, 0, stream>>>(latent, ln1_w, ln1_b, nx);

  // QKV projection (fused, N=2304), 128x128 tiles
  gemm128<MODE_QKV><<<32 * 18, 256, 0, stream>>>(
      nx, WqkvT, MTOK, 2304, 768, bq, bk, bv,
      qb, kb, vTb, nullptr);

  // attention (flash v8, 8-way key split)
  flash_attn_kernel<<<24 * 64, 512, 0, stream>>>(qb, kb, vTb, ctx);

  // output projection + residual -> x1 (fp32), 64x64 tiles
  gemm64r<<<64 * 12, 256, 0, stream>>>(
      ctx, WoT, MTOK, 768, 768, bo, latent, x1);

  // LN2
  ln_kernel<<<MTOK, 256, 0, stream>>>(x1, ln2_w, ln2_b, nx2);

  // FFN up + GELU -> hbuf (bf16), 128x128 tiles
  gemm128<MODE_GELU><<<32 * 24, 256, 0, stream>>>(
      nx2, W1T, MTOK, 3072, 768, b1, nullptr, nullptr,
      nullptr, nullptr, nullptr, hbuf);

  // FFN down + residual -> d_out (fp32), 64x64 tiles
  gemm64r<<<64 * 12, 256, 0, stream>>>(
      hbuf, W2T, MTOK, 768, 3072, b2, x1, out);
}

// Round 9
// 296.373 us; speedup vs baseline: 1.1889x; 1.1889x over previous
//
#include <hip/hip_runtime.h>

#define H 768
#define FF 3072
#define NH 12
#define DH 64
#define SEQ 2048
#define MTOK 4096

typedef __attribute__((ext_vector_type(8))) short short8;
typedef __attribute__((ext_vector_type(4))) float f32x4;

__device__ __forceinline__ f32x4 mfma16(short8 a, short8 b, f32x4 c) {
  return __builtin_amdgcn_mfma_f32_16x16x32_bf16(a, b, c, 0, 0, 0);
}

__device__ __forceinline__ unsigned short f2bf(float f) {
  union { float f; unsigned int u; } c; c.f = f;
  unsigned int u = c.u;
  u += 0x7fffu + ((u >> 16) & 1u);  // round-to-nearest-even
  return (unsigned short)(u >> 16);
}
__device__ __forceinline__ float bf2f(unsigned short s) {
  union { unsigned int u; float f; } c; c.u = ((unsigned int)s) << 16;
  return c.f;
}
__device__ __forceinline__ unsigned int pk2bf(float lo, float hi) {
  return (unsigned int)f2bf(lo) | ((unsigned int)f2bf(hi) << 16);
}
// truncating bf16 pair pack: one v_perm_b32
__device__ __forceinline__ unsigned int pktrunc(float lo, float hi) {
  union { float f; unsigned int u; } a, b; a.f = hi; b.f = lo;
  return __builtin_amdgcn_perm(a.u, b.u, 0x07060302u);
}

// async global->LDS, 16B per lane; LDS dest = wave-uniform base + lane*16
__device__ __forceinline__ void gld16(const unsigned short* g, unsigned short* l) {
  __builtin_amdgcn_global_load_lds(
      (const __attribute__((address_space(1))) void*)g,
      (__attribute__((address_space(3))) void*)l, 16, 0, 0);
}

// ---------------- fused: weight transposes (bid<6912) + LN1 (bid>=6912) ----------------
__global__ __launch_bounds__(256) void prep_kernel(
    const float* __restrict__ Wq, const float* __restrict__ Wk,
    const float* __restrict__ Wv, const float* __restrict__ Wo,
    const float* __restrict__ W1, const float* __restrict__ W2,
    unsigned short* __restrict__ WqkvT, unsigned short* __restrict__ WoT,
    unsigned short* __restrict__ W1T, unsigned short* __restrict__ W2T,
    const float* __restrict__ latent, const float* __restrict__ ln1_w,
    const float* __restrict__ ln1_b, unsigned short* __restrict__ nx) {
  int bid = blockIdx.x;
  int tid = threadIdx.x;
  if (bid >= 6912) {
    // LayerNorm row
    int row = bid - 6912;
    const float* xr = latent + (size_t)row * H;
    float v0 = xr[tid], v1 = xr[tid + 256], v2 = xr[tid + 512];
    float s = v0 + v1 + v2;
    float ss = v0 * v0 + v1 * v1 + v2 * v2;
#pragma unroll
    for (int off = 32; off > 0; off >>= 1) {
      s += __shfl_down(s, off);
      ss += __shfl_down(ss, off);
    }
    __shared__ float red[8];
    int wave = tid >> 6, lane = tid & 63;
    if (lane == 0) { red[wave] = s; red[4 + wave] = ss; }
    __syncthreads();
    s = red[0] + red[1] + red[2] + red[3];
    ss = red[4] + red[5] + red[6] + red[7];
    float mu = s * (1.0f / H);
    float var = ss * (1.0f / H) - mu * mu;
    float rs = rsqrtf(var + 1e-6f);
    unsigned short* orow = nx + (size_t)row * H;
    orow[tid]       = f2bf((v0 - mu) * rs * ln1_w[tid]       + ln1_b[tid]);
    orow[tid + 256] = f2bf((v1 - mu) * rs * ln1_w[tid + 256] + ln1_b[tid + 256]);
    orow[tid + 512] = f2bf((v2 - mu) * rs * ln1_w[tid + 512] + ln1_b[tid + 512]);
    return;
  }
  const float* in; unsigned short* out; int K, N, t0;
  if (bid < 1728) {
    K = 768; N = 768;
    if (bid < 576)       { in = Wq; out = WqkvT;                       t0 = bid; }
    else if (bid < 1152) { in = Wk; out = WqkvT + (size_t)768 * 768;   t0 = bid - 576; }
    else                 { in = Wv; out = WqkvT + (size_t)1536 * 768;  t0 = bid - 1152; }
  } else if (bid < 2304) { in = Wo; out = WoT; K = 768;  N = 768;  t0 = bid - 1728; }
  else if (bid < 4608)   { in = W1; out = W1T; K = 768;  N = 3072; t0 = bid - 2304; }
  else                   { in = W2; out = W2T; K = 3072; N = 768;  t0 = bid - 4608; }

  __shared__ float tile[32][33];
  int nb = N >> 5;
  int n0 = (t0 % nb) << 5;
  int k0 = (t0 / nb) << 5;
  int tx = tid & 31, ty = tid >> 5;
#pragma unroll
  for (int yy = 0; yy < 4; ++yy)
    tile[ty + yy * 8][tx] = in[(size_t)(k0 + ty + yy * 8) * N + n0 + tx];
  __syncthreads();
#pragma unroll
  for (int yy = 0; yy < 4; ++yy)
    out[(size_t)(n0 + ty + yy * 8) * K + k0 + tx] = f2bf(tile[tx][ty + yy * 8]);
}

// ---------------- LayerNorm fp32 [rows][768] -> bf16 ----------------
__global__ __launch_bounds__(256) void ln_kernel(const float* __restrict__ x,
                                                 const float* __restrict__ w,
                                                 const float* __restrict__ b,
                                                 unsigned short* __restrict__ out) {
  int row = blockIdx.x;
  int tid = threadIdx.x;
  const float* xr = x + (size_t)row * H;
  float v0 = xr[tid], v1 = xr[tid + 256], v2 = xr[tid + 512];
  float s = v0 + v1 + v2;
  float ss = v0 * v0 + v1 * v1 + v2 * v2;
#pragma unroll
  for (int off = 32; off > 0; off >>= 1) {
    s += __shfl_down(s, off);
    ss += __shfl_down(ss, off);
  }
  __shared__ float red[8];
  int wave = tid >> 6, lane = tid & 63;
  if (lane == 0) { red[wave] = s; red[4 + wave] = ss; }
  __syncthreads();
  s = red[0] + red[1] + red[2] + red[3];
  ss = red[4] + red[5] + red[6] + red[7];
  float mu = s * (1.0f / H);
  float var = ss * (1.0f / H) - mu * mu;
  float rs = rsqrtf(var + 1e-6f);
  unsigned short* orow = out + (size_t)row * H;
  orow[tid]       = f2bf((v0 - mu) * rs * w[tid]       + b[tid]);
  orow[tid + 256] = f2bf((v1 - mu) * rs * w[tid + 256] + b[tid + 256]);
  orow[tid + 512] = f2bf((v2 - mu) * rs * w[tid + 512] + b[tid + 512]);
}

// ---------------- GEMM m97-style: 128x128 tile, BK=32, global_load_lds w16 ----------------
// K' layout (per bh, per 32-key chunk c): shorts offset =
//   c*2048 + sub*1024 + dhh*512 + k16*32 + (dh&31),  sub=(key>>4)&1, k16=key&15, dhh=dh>>5
// V' layout (per bh, per chunk c): c*2048 + dt*512 + quad'*128 + l16'*8 + j
//   dt=d>>4, l16'=d&15, quad'=(key>>3)&3, j=key&7
enum { MODE_QKV = 0, MODE_RESID = 1, MODE_GELU = 2 };

template <int MODE>
__global__ __launch_bounds__(256) void gemm128(
    const unsigned short* __restrict__ A,   // [M,K] bf16
    const unsigned short* __restrict__ Bt,  // [N,K] bf16
    int M, int N, int K,
    const float* __restrict__ bias0,
    const float* __restrict__ bias1,
    const float* __restrict__ bias2,
    unsigned short* __restrict__ out_q,
    unsigned short* __restrict__ out_k,    // K' layout
    unsigned short* __restrict__ out_vT,   // V' layout
    unsigned short* __restrict__ out_bf)   // bf16 [M,N]
{
  const int nb = N >> 7;
  int n0 = (blockIdx.x % nb) << 7;
  int m0 = (blockIdx.x / nb) << 7;
  int tid = threadIdx.x;
  int wave = tid >> 6, lane = tid & 63;
  int quad = lane >> 4, l16 = lane & 15;
  int wm = (wave & 1) << 6;
  int wn = (wave >> 1) << 6;

  __shared__ __align__(16) unsigned short As[128 * 32];
  __shared__ __align__(16) unsigned short Bs[128 * 32];

  f32x4 acc[4][4];
#pragma unroll
  for (int i = 0; i < 4; ++i)
#pragma unroll
    for (int j = 0; j < 4; ++j) acc[i][j] = (f32x4){0.f, 0.f, 0.f, 0.f};

  int srow = lane >> 2;
  int scol = (lane & 3) << 3;
  const unsigned short* gA0 = A + (size_t)(m0 + wave * 32 + srow) * K + scol;
  const unsigned short* gA1 = gA0 + (size_t)16 * K;
  unsigned short* lA0 = &As[(wave * 32) * 32];
  unsigned short* lA1 = &As[(wave * 32 + 16) * 32];
  const unsigned short* gB0 = Bt + (size_t)(n0 + wave * 32 + srow) * K + scol;
  const unsigned short* gB1 = gB0 + (size_t)16 * K;
  unsigned short* lB0 = &Bs[(wave * 32) * 32];
  unsigned short* lB1 = &Bs[(wave * 32 + 16) * 32];

  for (int k0 = 0; k0 < K; k0 += 32) {
    gld16(gA0 + k0, lA0);
    gld16(gA1 + k0, lA1);
    gld16(gB0 + k0, lB0);
    gld16(gB1 + k0, lB1);
    __syncthreads();
    short8 af[4], bfr[4];
#pragma unroll
    for (int t = 0; t < 4; ++t)
      af[t] = *(const short8*)(&As[(wm + t * 16 + l16) * 32 + quad * 8]);
#pragma unroll
    for (int t = 0; t < 4; ++t)
      bfr[t] = *(const short8*)(&Bs[(wn + t * 16 + l16) * 32 + quad * 8]);
#pragma unroll
    for (int i = 0; i < 4; ++i)
#pragma unroll
      for (int j = 0; j < 4; ++j)
        acc[i][j] = mfma16(af[i], bfr[j], acc[i][j]);
    __syncthreads();
  }

#pragma unroll
  for (int mt = 0; mt < 4; ++mt)
#pragma unroll
    for (int nt = 0; nt < 4; ++nt) {
      f32x4 c = acc[mt][nt];
      int m = m0 + wm + mt * 16 + quad * 4;
      int n = n0 + wn + nt * 16 + l16;
      if (MODE == MODE_QKV) {
        int bb = m >> 11, sIdx = m & 2047;
        if (n < 768) {
          float bs = bias0[n];
          int hh = n >> 6, d = n & 63;
          unsigned short* dst = out_q + (((size_t)(bb * NH + hh)) * SEQ + sIdx) * DH + d;
#pragma unroll
          for (int r = 0; r < 4; ++r) dst[r * DH] = f2bf(c[r] + bs);
        } else if (n < 1536) {
          int nn = n - 768;
          float bs = bias1[nn];
          int hh = nn >> 6, d = nn & 63;
          // K' chunk layout
          size_t base = (size_t)(bb * NH + hh) * (SEQ * DH)
                      + (size_t)(sIdx >> 5) * 2048 + ((sIdx >> 4) & 1) * 1024
                      + (d >> 5) * 512 + (sIdx & 15) * 32 + (d & 31);
#pragma unroll
          for (int r = 0; r < 4; ++r) out_k[base + r * 32] = f2bf(c[r] + bs);
        } else {
          int nn = n - 1536;
          float bs = bias2[nn];
          int hh = nn >> 6, d = nn & 63;
          // V' chunk layout; keys sIdx..sIdx+3 contiguous in j
          size_t base = (size_t)(bb * NH + hh) * (SEQ * DH)
                      + (size_t)(sIdx >> 5) * 2048 + (d >> 4) * 512
                      + ((sIdx >> 3) & 3) * 128 + (d & 15) * 8 + (sIdx & 7);
          uint2 pk;
          pk.x = pk2bf(c[0] + bs, c[1] + bs);
          pk.y = pk2bf(c[2] + bs, c[3] + bs);
          *(uint2*)(out_vT + base) = pk;
        }
      } else {  // MODE_GELU
        float bs = bias0[n];
        unsigned short* op = out_bf + (size_t)m * N + n;
#pragma unroll
        for (int r = 0; r < 4; ++r) {
          float t = c[r] + bs;
          op[(size_t)r * N] = f2bf(0.5f * t * (1.0f + erff(t * 0.70710678118654752f)));
        }
      }
    }
}

// ---------------- GEMM 64x64 tile (for N=768 shapes): residual epilogue ----------------
__global__ __launch_bounds__(256) void gemm64r(
    const unsigned short* __restrict__ A,   // [M,K]
    const unsigned short* __restrict__ Bt,  // [N,K]
    int M, int N, int K,
    const float* __restrict__ bias0,
    const float* __restrict__ resid,        // fp32 [M,N]
    float* __restrict__ out_f)              // fp32 [M,N]
{
  const int nb = N >> 6;
  int n0 = (blockIdx.x % nb) << 6;
  int m0 = (blockIdx.x / nb) << 6;
  int tid = threadIdx.x;
  int wave = tid >> 6, lane = tid & 63;
  int quad = lane >> 4, l16 = lane & 15;
  int wm = (wave & 1) << 5;
  int wn = (wave >> 1) << 5;

  __shared__ __align__(16) unsigned short As[64 * 32];
  __shared__ __align__(16) unsigned short Bs[64 * 32];

  f32x4 acc[2][2];
#pragma unroll
  for (int i = 0; i < 2; ++i)
#pragma unroll
    for (int j = 0; j < 2; ++j) acc[i][j] = (f32x4){0.f, 0.f, 0.f, 0.f};

  int srow = lane >> 2;
  int scol = (lane & 3) << 3;
  const unsigned short* gA = A + (size_t)(m0 + wave * 16 + srow) * K + scol;
  unsigned short* lA = &As[(wave * 16) * 32];
  const unsigned short* gB = Bt + (size_t)(n0 + wave * 16 + srow) * K + scol;
  unsigned short* lB = &Bs[(wave * 16) * 32];

  for (int k0 = 0; k0 < K; k0 += 32) {
    gld16(gA + k0, lA);
    gld16(gB + k0, lB);
    __syncthreads();
    short8 af[2], bfr[2];
#pragma unroll
    for (int t = 0; t < 2; ++t)
      af[t] = *(const short8*)(&As[(wm + t * 16 + l16) * 32 + quad * 8]);
#pragma unroll
    for (int t = 0; t < 2; ++t)
      bfr[t] = *(const short8*)(&Bs[(wn + t * 16 + l16) * 32 + quad * 8]);
#pragma unroll
    for (int i = 0; i < 2; ++i)
#pragma unroll
      for (int j = 0; j < 2; ++j)
        acc[i][j] = mfma16(af[i], bfr[j], acc[i][j]);
    __syncthreads();
  }

#pragma unroll
  for (int mt = 0; mt < 2; ++mt)
#pragma unroll
    for (int nt = 0; nt < 2; ++nt) {
      f32x4 c = acc[mt][nt];
      int m = m0 + wm + mt * 16 + quad * 4;
      int n = n0 + wn + nt * 16 + l16;
      float bs = bias0[n];
      const float* rp = resid + (size_t)m * N + n;
      float* op = out_f + (size_t)m * N + n;
#pragma unroll
      for (int r = 0; r < 4; ++r) op[(size_t)r * N] = rp[(size_t)r * N] + c[r] + bs;
    }
}

// ---------------- flash attention v9: v7 structure + lane-dense K'/V' loads ----------------
// Block = 32 q-rows (2 tiles), 4 waves key-split (512 keys, 16 iters of 32).
// All 8 loads/iter are contiguous 1KB (base + lane-linear*16B) thanks to the
// K'/V' chunk layouts written by the QKV epilogue. Body otherwise = v7:
// no max, unnormalized exp, bpermute P^T, LDS combine.
__global__ __launch_bounds__(256, 4) void flash_attn_kernel(
    const unsigned short* __restrict__ q,   // [B,NH,S,DH]
    const unsigned short* __restrict__ k,   // K' layout
    const unsigned short* __restrict__ vT,  // V' layout
    unsigned short* __restrict__ ctx)       // [MTOK,H] bf16
{
  const float CEXP = 0.18033688011112042f;  // (1/8) * log2(e)
  int bh = blockIdx.x % 24;
  int qblk = blockIdx.x / 24;
  int b = bh / NH, h = bh % NH;
  int tid = threadIdx.x;
  int wave = tid >> 6, lane = tid & 63;
  int quad = lane >> 4, l16 = lane & 15;
  int qbase = qblk << 5;

  const unsigned short* qp = q + ((size_t)bh * SEQ + qbase) * DH;
  const unsigned short* kbh = k + (size_t)bh * (SEQ * DH);
  const unsigned short* vbh = vT + (size_t)bh * (SEQ * DH);

  short8 qf00 = *(const short8*)(qp + l16 * DH + quad * 8);
  short8 qf01 = *(const short8*)(qp + l16 * DH + 32 + quad * 8);
  short8 qf10 = *(const short8*)(qp + (16 + l16) * DH + quad * 8);
  short8 qf11 = *(const short8*)(qp + (16 + l16) * DH + 32 + quad * 8);

  f32x4 oacc[2][4];
#pragma unroll
  for (int t = 0; t < 2; ++t)
#pragma unroll
    for (int dt = 0; dt < 4; ++dt) oacc[t][dt] = (f32x4){0.f, 0.f, 0.f, 0.f};
  float L[2] = {0.f, 0.f};

  int addrA = ((((2 * quad) & 3) << 4) + l16) << 2;
  int addrB = ((((2 * quad + 1) & 3) << 4) + l16) << 2;
  bool loquad = quad < 2;

  int klin = (l16 * 4 + quad) * 8;   // K' lane offset (shorts)
  int vlin = (quad * 16 + l16) * 8;  // V' lane offset (shorts)

  int keylo = wave << 9;
  for (int key0 = keylo; key0 < keylo + 512; key0 += 32) {
    int cbase = (key0 >> 5) * 2048;
    short8 ka0 = *(const short8*)(kbh + cbase + klin);
    short8 ka1 = *(const short8*)(kbh + cbase + 512 + klin);
    short8 kb0 = *(const short8*)(kbh + cbase + 1024 + klin);
    short8 kb1 = *(const short8*)(kbh + cbase + 1536 + klin);
    short8 vf0 = *(const short8*)(vbh + cbase + 0 * 512 + vlin);
    short8 vf1 = *(const short8*)(vbh + cbase + 1 * 512 + vlin);
    short8 vf2 = *(const short8*)(vbh + cbase + 2 * 512 + vlin);
    short8 vf3 = *(const short8*)(vbh + cbase + 3 * 512 + vlin);

#pragma unroll
    for (int t = 0; t < 2; ++t) {
      short8 q0 = t ? qf10 : qf00;
      short8 q1 = t ? qf11 : qf01;
      f32x4 s0 = (f32x4){0.f, 0.f, 0.f, 0.f};
      f32x4 s1 = (f32x4){0.f, 0.f, 0.f, 0.f};
      s0 = mfma16(ka0, q0, s0);
      s0 = mfma16(ka1, q1, s0);
      s1 = mfma16(kb0, q0, s1);
      s1 = mfma16(kb1, q1, s1);

      f32x4 p0, p1;
#pragma unroll
      for (int r = 0; r < 4; ++r) {
        p0[r] = __builtin_amdgcn_exp2f(s0[r] * CEXP);
        p1[r] = __builtin_amdgcn_exp2f(s1[r] * CEXP);
      }
      L[t] += (p0[0] + p0[1]) + (p0[2] + p0[3]) + (p1[0] + p1[1]) + (p1[2] + p1[3]);

      int d00 = (int)pktrunc(p0[0], p0[1]);
      int d01 = (int)pktrunc(p0[2], p0[3]);
      int d10 = (int)pktrunc(p1[0], p1[1]);
      int d11 = (int)pktrunc(p1[2], p1[3]);

      int f0a = __builtin_amdgcn_ds_bpermute(addrA, d00);
      int f0b = __builtin_amdgcn_ds_bpermute(addrA, d10);
      int f1a = __builtin_amdgcn_ds_bpermute(addrA, d01);
      int f1b = __builtin_amdgcn_ds_bpermute(addrA, d11);
      int f2a = __builtin_amdgcn_ds_bpermute(addrB, d00);
      int f2b = __builtin_amdgcn_ds_bpermute(addrB, d10);
      int f3a = __builtin_amdgcn_ds_bpermute(addrB, d01);
      int f3b = __builtin_amdgcn_ds_bpermute(addrB, d11);
      union { short8 s; int i[4]; } pf;
      pf.i[0] = loquad ? f0a : f0b;
      pf.i[1] = loquad ? f1a : f1b;
      pf.i[2] = loquad ? f2a : f2b;
      pf.i[3] = loquad ? f3a : f3b;

      oacc[t][0] = mfma16(vf0, pf.s, oacc[t][0]);
      oacc[t][1] = mfma16(vf1, pf.s, oacc[t][1]);
      oacc[t][2] = mfma16(vf2, pf.s, oacc[t][2]);
      oacc[t][3] = mfma16(vf3, pf.s, oacc[t][3]);
    }
  }

#pragma unroll
  for (int t = 0; t < 2; ++t) {
    L[t] += __shfl_xor(L[t], 16);
    L[t] += __shfl_xor(L[t], 32);
  }

  __shared__ float lbuf[4][2][16];
  __shared__ uint2 obuf[4][2][4][64];

  if (lane < 16) {
    lbuf[wave][0][lane] = L[0];
    lbuf[wave][1][lane] = L[1];
  }
#pragma unroll
  for (int t = 0; t < 2; ++t)
#pragma unroll
    for (int dt = 0; dt < 4; ++dt) {
      uint2 pk;
      pk.x = pk2bf(oacc[t][dt][0], oacc[t][dt][1]);
      pk.y = pk2bf(oacc[t][dt][2], oacc[t][dt][3]);
      obuf[wave][t][dt][lane] = pk;
    }
  __syncthreads();

#pragma unroll
  for (int pp = 0; pp < 2; ++pp) {
    int pi = wave * 2 + pp;
    int t = pi >> 2, dt = pi & 3;
    f32x4 sum = (f32x4){0.f, 0.f, 0.f, 0.f};
#pragma unroll
    for (int w = 0; w < 4; ++w) {
      uint2 pk = obuf[w][t][dt][lane];
      sum[0] += bf2f((unsigned short)(pk.x & 0xffff));
      sum[1] += bf2f((unsigned short)(pk.x >> 16));
      sum[2] += bf2f((unsigned short)(pk.y & 0xffff));
      sum[3] += bf2f((unsigned short)(pk.y >> 16));
    }
    float lstar = lbuf[0][t][l16] + lbuf[1][t][l16] + lbuf[2][t][l16] + lbuf[3][t][l16];
    float rinv = 1.0f / lstar;
    uint2 res;
    res.x = pk2bf(sum[0] * rinv, sum[1] * rinv);
    res.y = pk2bf(sum[2] * rinv, sum[3] * rinv);
    unsigned short* crow = ctx + (size_t)(b * SEQ + qbase + t * 16 + l16) * H
                           + h * DH + dt * 16 + quad * 4;
    *(uint2*)crow = res;
  }
}

// ---------------- launch ----------------
extern "C" void kernel_launch(void* const* d_in, const int* in_sizes, int n_in,
                              void* d_out, int out_size, void* d_ws, size_t ws_size,
                              hipStream_t stream) {
  const float* latent = (const float*)d_in[0];
  const float* ln1_w = (const float*)d_in[1];
  const float* ln1_b = (const float*)d_in[2];
  const float* Wq = (const float*)d_in[3];
  const float* bq = (const float*)d_in[4];
  const float* Wk = (const float*)d_in[5];
  const float* bk = (const float*)d_in[6];
  const float* Wv = (const float*)d_in[7];
  const float* bv = (const float*)d_in[8];
  const float* Wo = (const float*)d_in[9];
  const float* bo = (const float*)d_in[10];
  const float* ln2_w = (const float*)d_in[11];
  const float* ln2_b = (const float*)d_in[12];
  const float* W1 = (const float*)d_in[13];
  const float* b1 = (const float*)d_in[14];
  const float* W2 = (const float*)d_in[15];
  const float* b2 = (const float*)d_in[16];
  float* out = (float*)d_out;

  char* ws = (char*)d_ws;
  unsigned short* WqkvT = (unsigned short*)ws; ws += (size_t)2304 * 768 * 2;
  unsigned short* WoT   = (unsigned short*)ws; ws += (size_t)768 * 768 * 2;
  unsigned short* W1T   = (unsigned short*)ws; ws += (size_t)3072 * 768 * 2;
  unsigned short* W2T   = (unsigned short*)ws; ws += (size_t)768 * 3072 * 2;
  unsigned short* nx    = (unsigned short*)ws; ws += (size_t)MTOK * H * 2;
  unsigned short* nx2   = (unsigned short*)ws; ws += (size_t)MTOK * H * 2;
  unsigned short* qb    = (unsigned short*)ws; ws += (size_t)MTOK * H * 2;
  unsigned short* kb    = (unsigned short*)ws; ws += (size_t)MTOK * H * 2;
  unsigned short* vTb   = (unsigned short*)ws; ws += (size_t)MTOK * H * 2;
  unsigned short* ctx   = (unsigned short*)ws; ws += (size_t)MTOK * H * 2;
  unsigned short* hbuf  = (unsigned short*)ws; ws += (size_t)MTOK * FF * 2;
  float* x1             = (float*)ws;          ws += (size_t)MTOK * H * 4;

  // weight transposes + LN1, one launch
  prep_kernel<<<6912 + MTOK, 256, 0, stream>>>(
      Wq, Wk, Wv, Wo, W1, W2, WqkvT, WoT, W1T, W2T,
      latent, ln1_w, ln1_b, nx);

  // QKV projection (fused, N=2304), 128x128 tiles; K/V written in K'/V' layouts
  gemm128<MODE_QKV><<<32 * 18, 256, 0, stream>>>(
      nx, WqkvT, MTOK, 2304, 768, bq, bk, bv,
      qb, kb, vTb, nullptr);

  // attention (flash v9, dense loads)
  flash_attn_kernel<<<24 * 64, 256, 0, stream>>>(qb, kb, vTb, ctx);

  // output projection + residual -> x1 (fp32), 64x64 tiles
  gemm64r<<<64 * 12, 256, 0, stream>>>(
      ctx, WoT, MTOK, 768, 768, bo, latent, x1);

  // LN2
  ln_kernel<<<MTOK, 256, 0, stream>>>(x1, ln2_w, ln2_b, nx2);

  // FFN up + GELU -> hbuf (bf16), 128x128 tiles
  gemm128<MODE_GELU><<<32 * 24, 256, 0, stream>>>(
      nx2, W1T, MTOK, 3072, 768, b1, nullptr, nullptr,
      nullptr, nullptr, nullptr, hbuf);

  // FFN down + residual -> d_out (fp32), 64x64 tiles
  gemm64r<<<64 * 12, 256, 0, stream>>>(
      hbuf, W2T, MTOK, 768, 3072, b2, x1, out);
}

// Round 10
// 277.929 us; speedup vs baseline: 1.2678x; 1.0664x over previous
//
#include <hip/hip_runtime.h>

#define H 768
#define FF 3072
#define NH 12
#define DH 64
#define SEQ 2048
#define MTOK 4096

typedef __attribute__((ext_vector_type(8))) short short8;
typedef __attribute__((ext_vector_type(4))) float f32x4;

__device__ __forceinline__ f32x4 mfma16(short8 a, short8 b, f32x4 c) {
  return __builtin_amdgcn_mfma_f32_16x16x32_bf16(a, b, c, 0, 0, 0);
}

__device__ __forceinline__ unsigned short f2bf(float f) {
  union { float f; unsigned int u; } c; c.f = f;
  unsigned int u = c.u;
  u += 0x7fffu + ((u >> 16) & 1u);  // round-to-nearest-even
  return (unsigned short)(u >> 16);
}
__device__ __forceinline__ float bf2f(unsigned short s) {
  union { unsigned int u; float f; } c; c.u = ((unsigned int)s) << 16;
  return c.f;
}
__device__ __forceinline__ unsigned int pk2bf(float lo, float hi) {
  return (unsigned int)f2bf(lo) | ((unsigned int)f2bf(hi) << 16);
}
// truncating bf16 pair pack: one v_perm_b32
__device__ __forceinline__ unsigned int pktrunc(float lo, float hi) {
  union { float f; unsigned int u; } a, b; a.f = hi; b.f = lo;
  return __builtin_amdgcn_perm(a.u, b.u, 0x07060302u);
}

// async global->LDS, 16B per lane; LDS dest = wave-uniform base + lane*16
__device__ __forceinline__ void gld16(const unsigned short* g, unsigned short* l) {
  __builtin_amdgcn_global_load_lds(
      (const __attribute__((address_space(1))) void*)g,
      (__attribute__((address_space(3))) void*)l, 16, 0, 0);
}

// ---------------- fused: weight transposes (bid<6912) + LN1 (bid>=6912) ----------------
__global__ __launch_bounds__(256) void prep_kernel(
    const float* __restrict__ Wq, const float* __restrict__ Wk,
    const float* __restrict__ Wv, const float* __restrict__ Wo,
    const float* __restrict__ W1, const float* __restrict__ W2,
    unsigned short* __restrict__ WqkvT, unsigned short* __restrict__ WoT,
    unsigned short* __restrict__ W1T, unsigned short* __restrict__ W2T,
    const float* __restrict__ latent, const float* __restrict__ ln1_w,
    const float* __restrict__ ln1_b, unsigned short* __restrict__ nx) {
  int bid = blockIdx.x;
  int tid = threadIdx.x;
  if (bid >= 6912) {
    int row = bid - 6912;
    const float* xr = latent + (size_t)row * H;
    float v0 = xr[tid], v1 = xr[tid + 256], v2 = xr[tid + 512];
    float s = v0 + v1 + v2;
    float ss = v0 * v0 + v1 * v1 + v2 * v2;
#pragma unroll
    for (int off = 32; off > 0; off >>= 1) {
      s += __shfl_down(s, off);
      ss += __shfl_down(ss, off);
    }
    __shared__ float red[8];
    int wave = tid >> 6, lane = tid & 63;
    if (lane == 0) { red[wave] = s; red[4 + wave] = ss; }
    __syncthreads();
    s = red[0] + red[1] + red[2] + red[3];
    ss = red[4] + red[5] + red[6] + red[7];
    float mu = s * (1.0f / H);
    float var = ss * (1.0f / H) - mu * mu;
    float rs = rsqrtf(var + 1e-6f);
    unsigned short* orow = nx + (size_t)row * H;
    orow[tid]       = f2bf((v0 - mu) * rs * ln1_w[tid]       + ln1_b[tid]);
    orow[tid + 256] = f2bf((v1 - mu) * rs * ln1_w[tid + 256] + ln1_b[tid + 256]);
    orow[tid + 512] = f2bf((v2 - mu) * rs * ln1_w[tid + 512] + ln1_b[tid + 512]);
    return;
  }
  const float* in; unsigned short* out; int K, N, t0;
  if (bid < 1728) {
    K = 768; N = 768;
    if (bid < 576)       { in = Wq; out = WqkvT;                       t0 = bid; }
    else if (bid < 1152) { in = Wk; out = WqkvT + (size_t)768 * 768;   t0 = bid - 576; }
    else                 { in = Wv; out = WqkvT + (size_t)1536 * 768;  t0 = bid - 1152; }
  } else if (bid < 2304) { in = Wo; out = WoT; K = 768;  N = 768;  t0 = bid - 1728; }
  else if (bid < 4608)   { in = W1; out = W1T; K = 768;  N = 3072; t0 = bid - 2304; }
  else                   { in = W2; out = W2T; K = 3072; N = 768;  t0 = bid - 4608; }

  __shared__ float tile[32][33];
  int nb = N >> 5;
  int n0 = (t0 % nb) << 5;
  int k0 = (t0 / nb) << 5;
  int tx = tid & 31, ty = tid >> 5;
#pragma unroll
  for (int yy = 0; yy < 4; ++yy)
    tile[ty + yy * 8][tx] = in[(size_t)(k0 + ty + yy * 8) * N + n0 + tx];
  __syncthreads();
#pragma unroll
  for (int yy = 0; yy < 4; ++yy)
    out[(size_t)(n0 + ty + yy * 8) * K + k0 + tx] = f2bf(tile[tx][ty + yy * 8]);
}

// ---------------- LayerNorm fp32 [rows][768] -> bf16 ----------------
__global__ __launch_bounds__(256) void ln_kernel(const float* __restrict__ x,
                                                 const float* __restrict__ w,
                                                 const float* __restrict__ b,
                                                 unsigned short* __restrict__ out) {
  int row = blockIdx.x;
  int tid = threadIdx.x;
  const float* xr = x + (size_t)row * H;
  float v0 = xr[tid], v1 = xr[tid + 256], v2 = xr[tid + 512];
  float s = v0 + v1 + v2;
  float ss = v0 * v0 + v1 * v1 + v2 * v2;
#pragma unroll
  for (int off = 32; off > 0; off >>= 1) {
    s += __shfl_down(s, off);
    ss += __shfl_down(ss, off);
  }
  __shared__ float red[8];
  int wave = tid >> 6, lane = tid & 63;
  if (lane == 0) { red[wave] = s; red[4 + wave] = ss; }
  __syncthreads();
  s = red[0] + red[1] + red[2] + red[3];
  ss = red[4] + red[5] + red[6] + red[7];
  float mu = s * (1.0f / H);
  float var = ss * (1.0f / H) - mu * mu;
  float rs = rsqrtf(var + 1e-6f);
  unsigned short* orow = out + (size_t)row * H;
  orow[tid]       = f2bf((v0 - mu) * rs * w[tid]       + b[tid]);
  orow[tid + 256] = f2bf((v1 - mu) * rs * w[tid + 256] + b[tid + 256]);
  orow[tid + 512] = f2bf((v2 - mu) * rs * w[tid + 512] + b[tid + 512]);
}

// ---------------- GEMM m97-style: 128x128 tile, BK=32, global_load_lds w16 ----------------
// K' layout (per bh, per 32-key chunk c): shorts offset =
//   c*2048 + sub*1024 + dhh*512 + k16*32 + (dh&31)
// V' layout (per bh, per chunk c): c*2048 + dt*512 + quad'*128 + l16'*8 + j
enum { MODE_QKV = 0, MODE_RESID = 1, MODE_GELU = 2 };

template <int MODE>
__global__ __launch_bounds__(256) void gemm128(
    const unsigned short* __restrict__ A,   // [M,K] bf16
    const unsigned short* __restrict__ Bt,  // [N,K] bf16
    int M, int N, int K,
    const float* __restrict__ bias0,
    const float* __restrict__ bias1,
    const float* __restrict__ bias2,
    unsigned short* __restrict__ out_q,
    unsigned short* __restrict__ out_k,    // K' layout
    unsigned short* __restrict__ out_vT,   // V' layout
    unsigned short* __restrict__ out_bf)   // bf16 [M,N]
{
  const int mb = M >> 7;
  int m0 = (blockIdx.x % mb) << 7;        // m-major: same n-strip stays adjacent
  int n0 = (blockIdx.x / mb) << 7;
  int tid = threadIdx.x;
  int wave = tid >> 6, lane = tid & 63;
  int quad = lane >> 4, l16 = lane & 15;
  int wm = (wave & 1) << 6;
  int wn = (wave >> 1) << 6;

  __shared__ __align__(16) unsigned short As[128 * 32];
  __shared__ __align__(16) unsigned short Bs[128 * 32];

  f32x4 acc[4][4];
#pragma unroll
  for (int i = 0; i < 4; ++i)
#pragma unroll
    for (int j = 0; j < 4; ++j) acc[i][j] = (f32x4){0.f, 0.f, 0.f, 0.f};

  int srow = lane >> 2;
  int scol = (lane & 3) << 3;
  const unsigned short* gA0 = A + (size_t)(m0 + wave * 32 + srow) * K + scol;
  const unsigned short* gA1 = gA0 + (size_t)16 * K;
  unsigned short* lA0 = &As[(wave * 32) * 32];
  unsigned short* lA1 = &As[(wave * 32 + 16) * 32];
  const unsigned short* gB0 = Bt + (size_t)(n0 + wave * 32 + srow) * K + scol;
  const unsigned short* gB1 = gB0 + (size_t)16 * K;
  unsigned short* lB0 = &Bs[(wave * 32) * 32];
  unsigned short* lB1 = &Bs[(wave * 32 + 16) * 32];

  for (int k0 = 0; k0 < K; k0 += 32) {
    gld16(gA0 + k0, lA0);
    gld16(gA1 + k0, lA1);
    gld16(gB0 + k0, lB0);
    gld16(gB1 + k0, lB1);
    __syncthreads();
    short8 af[4], bfr[4];
#pragma unroll
    for (int t = 0; t < 4; ++t)
      af[t] = *(const short8*)(&As[(wm + t * 16 + l16) * 32 + quad * 8]);
#pragma unroll
    for (int t = 0; t < 4; ++t)
      bfr[t] = *(const short8*)(&Bs[(wn + t * 16 + l16) * 32 + quad * 8]);
#pragma unroll
    for (int i = 0; i < 4; ++i)
#pragma unroll
      for (int j = 0; j < 4; ++j)
        acc[i][j] = mfma16(af[i], bfr[j], acc[i][j]);
    __syncthreads();
  }

#pragma unroll
  for (int mt = 0; mt < 4; ++mt)
#pragma unroll
    for (int nt = 0; nt < 4; ++nt) {
      f32x4 c = acc[mt][nt];
      int m = m0 + wm + mt * 16 + quad * 4;
      int n = n0 + wn + nt * 16 + l16;
      if (MODE == MODE_QKV) {
        int bb = m >> 11, sIdx = m & 2047;
        if (n < 768) {
          float bs = bias0[n];
          int hh = n >> 6, d = n & 63;
          unsigned short* dst = out_q + (((size_t)(bb * NH + hh)) * SEQ + sIdx) * DH + d;
#pragma unroll
          for (int r = 0; r < 4; ++r) dst[r * DH] = f2bf(c[r] + bs);
        } else if (n < 1536) {
          int nn = n - 768;
          float bs = bias1[nn];
          int hh = nn >> 6, d = nn & 63;
          size_t base = (size_t)(bb * NH + hh) * (SEQ * DH)
                      + (size_t)(sIdx >> 5) * 2048 + ((sIdx >> 4) & 1) * 1024
                      + (d >> 5) * 512 + (sIdx & 15) * 32 + (d & 31);
#pragma unroll
          for (int r = 0; r < 4; ++r) out_k[base + r * 32] = f2bf(c[r] + bs);
        } else {
          int nn = n - 1536;
          float bs = bias2[nn];
          int hh = nn >> 6, d = nn & 63;
          size_t base = (size_t)(bb * NH + hh) * (SEQ * DH)
                      + (size_t)(sIdx >> 5) * 2048 + (d >> 4) * 512
                      + ((sIdx >> 3) & 3) * 128 + (d & 15) * 8 + (sIdx & 7);
          uint2 pk;
          pk.x = pk2bf(c[0] + bs, c[1] + bs);
          pk.y = pk2bf(c[2] + bs, c[3] + bs);
          *(uint2*)(out_vT + base) = pk;
        }
      } else {  // MODE_GELU
        float bs = bias0[n];
        unsigned short* op = out_bf + (size_t)m * N + n;
#pragma unroll
        for (int r = 0; r < 4; ++r) {
          float t = c[r] + bs;
          op[(size_t)r * N] = f2bf(0.5f * t * (1.0f + erff(t * 0.70710678118654752f)));
        }
      }
    }
}

// ---------------- GEMM 64x64 tile, BK=128 (4 chunk-buffers): residual epilogue ----------------
// Per outer iter each wave issues 8 gld16 (4 A + 4 B chunks), one barrier,
// then 16 ds_read_b128 + 16 mfma — 4x wider barrier window than BK=32.
__global__ __launch_bounds__(256) void gemm64r(
    const unsigned short* __restrict__ A,   // [M,K]
    const unsigned short* __restrict__ Bt,  // [N,K]
    int M, int N, int K,
    const float* __restrict__ bias0,
    const float* __restrict__ resid,        // fp32 [M,N]
    float* __restrict__ out_f)              // fp32 [M,N]
{
  const int mb = M >> 6;
  int m0 = (blockIdx.x % mb) << 6;        // m-major ordering
  int n0 = (blockIdx.x / mb) << 6;
  int tid = threadIdx.x;
  int wave = tid >> 6, lane = tid & 63;
  int quad = lane >> 4, l16 = lane & 15;
  int wm = (wave & 1) << 5;
  int wn = (wave >> 1) << 5;

  __shared__ __align__(16) unsigned short As[4][64 * 32];
  __shared__ __align__(16) unsigned short Bs[4][64 * 32];

  f32x4 acc[2][2];
#pragma unroll
  for (int i = 0; i < 2; ++i)
#pragma unroll
    for (int j = 0; j < 2; ++j) acc[i][j] = (f32x4){0.f, 0.f, 0.f, 0.f};

  int srow = lane >> 2;
  int scol = (lane & 3) << 3;
  const unsigned short* gA = A + (size_t)(m0 + wave * 16 + srow) * K + scol;
  const unsigned short* gB = Bt + (size_t)(n0 + wave * 16 + srow) * K + scol;
  unsigned short* lA = &As[0][(wave * 16) * 32];
  unsigned short* lB = &Bs[0][(wave * 16) * 32];
  const int CH = 64 * 32;   // chunk stride in shorts

  for (int k0 = 0; k0 < K; k0 += 128) {
#pragma unroll
    for (int kc = 0; kc < 4; ++kc) {
      gld16(gA + k0 + kc * 32, lA + kc * CH);
      gld16(gB + k0 + kc * 32, lB + kc * CH);
    }
    __syncthreads();
#pragma unroll
    for (int kc = 0; kc < 4; ++kc) {
      short8 af[2], bfr[2];
#pragma unroll
      for (int t = 0; t < 2; ++t)
        af[t] = *(const short8*)(&As[kc][(wm + t * 16 + l16) * 32 + quad * 8]);
#pragma unroll
      for (int t = 0; t < 2; ++t)
        bfr[t] = *(const short8*)(&Bs[kc][(wn + t * 16 + l16) * 32 + quad * 8]);
#pragma unroll
      for (int i = 0; i < 2; ++i)
#pragma unroll
        for (int j = 0; j < 2; ++j)
          acc[i][j] = mfma16(af[i], bfr[j], acc[i][j]);
    }
    __syncthreads();
  }

#pragma unroll
  for (int mt = 0; mt < 2; ++mt)
#pragma unroll
    for (int nt = 0; nt < 2; ++nt) {
      f32x4 c = acc[mt][nt];
      int m = m0 + wm + mt * 16 + quad * 4;
      int n = n0 + wn + nt * 16 + l16;
      float bs = bias0[n];
      const float* rp = resid + (size_t)m * N + n;
      float* op = out_f + (size_t)m * N + n;
#pragma unroll
      for (int r = 0; r < 4; ++r) op[(size_t)r * N] = rp[(size_t)r * N] + c[r] + bs;
    }
}

// ---------------- flash attention v9: v7 structure + lane-dense K'/V' loads ----------------
__global__ __launch_bounds__(256, 4) void flash_attn_kernel(
    const unsigned short* __restrict__ q,   // [B,NH,S,DH]
    const unsigned short* __restrict__ k,   // K' layout
    const unsigned short* __restrict__ vT,  // V' layout
    unsigned short* __restrict__ ctx)       // [MTOK,H] bf16
{
  const float CEXP = 0.18033688011112042f;  // (1/8) * log2(e)
  int bh = blockIdx.x % 24;
  int qblk = blockIdx.x / 24;
  int b = bh / NH, h = bh % NH;
  int tid = threadIdx.x;
  int wave = tid >> 6, lane = tid & 63;
  int quad = lane >> 4, l16 = lane & 15;
  int qbase = qblk << 5;

  const unsigned short* qp = q + ((size_t)bh * SEQ + qbase) * DH;
  const unsigned short* kbh = k + (size_t)bh * (SEQ * DH);
  const unsigned short* vbh = vT + (size_t)bh * (SEQ * DH);

  short8 qf00 = *(const short8*)(qp + l16 * DH + quad * 8);
  short8 qf01 = *(const short8*)(qp + l16 * DH + 32 + quad * 8);
  short8 qf10 = *(const short8*)(qp + (16 + l16) * DH + quad * 8);
  short8 qf11 = *(const short8*)(qp + (16 + l16) * DH + 32 + quad * 8);

  f32x4 oacc[2][4];
#pragma unroll
  for (int t = 0; t < 2; ++t)
#pragma unroll
    for (int dt = 0; dt < 4; ++dt) oacc[t][dt] = (f32x4){0.f, 0.f, 0.f, 0.f};
  float L[2] = {0.f, 0.f};

  int addrA = ((((2 * quad) & 3) << 4) + l16) << 2;
  int addrB = ((((2 * quad + 1) & 3) << 4) + l16) << 2;
  bool loquad = quad < 2;

  int klin = (l16 * 4 + quad) * 8;
  int vlin = (quad * 16 + l16) * 8;

  int keylo = wave << 9;
  for (int key0 = keylo; key0 < keylo + 512; key0 += 32) {
    int cbase = (key0 >> 5) * 2048;
    short8 ka0 = *(const short8*)(kbh + cbase + klin);
    short8 ka1 = *(const short8*)(kbh + cbase + 512 + klin);
    short8 kb0 = *(const short8*)(kbh + cbase + 1024 + klin);
    short8 kb1 = *(const short8*)(kbh + cbase + 1536 + klin);
    short8 vf0 = *(const short8*)(vbh + cbase + 0 * 512 + vlin);
    short8 vf1 = *(const short8*)(vbh + cbase + 1 * 512 + vlin);
    short8 vf2 = *(const short8*)(vbh + cbase + 2 * 512 + vlin);
    short8 vf3 = *(const short8*)(vbh + cbase + 3 * 512 + vlin);

#pragma unroll
    for (int t = 0; t < 2; ++t) {
      short8 q0 = t ? qf10 : qf00;
      short8 q1 = t ? qf11 : qf01;
      f32x4 s0 = (f32x4){0.f, 0.f, 0.f, 0.f};
      f32x4 s1 = (f32x4){0.f, 0.f, 0.f, 0.f};
      s0 = mfma16(ka0, q0, s0);
      s0 = mfma16(ka1, q1, s0);
      s1 = mfma16(kb0, q0, s1);
      s1 = mfma16(kb1, q1, s1);

      f32x4 p0, p1;
#pragma unroll
      for (int r = 0; r < 4; ++r) {
        p0[r] = __builtin_amdgcn_exp2f(s0[r] * CEXP);
        p1[r] = __builtin_amdgcn_exp2f(s1[r] * CEXP);
      }
      L[t] += (p0[0] + p0[1]) + (p0[2] + p0[3]) + (p1[0] + p1[1]) + (p1[2] + p1[3]);

      int d00 = (int)pktrunc(p0[0], p0[1]);
      int d01 = (int)pktrunc(p0[2], p0[3]);
      int d10 = (int)pktrunc(p1[0], p1[1]);
      int d11 = (int)pktrunc(p1[2], p1[3]);

      int f0a = __builtin_amdgcn_ds_bpermute(addrA, d00);
      int f0b = __builtin_amdgcn_ds_bpermute(addrA, d10);
      int f1a = __builtin_amdgcn_ds_bpermute(addrA, d01);
      int f1b = __builtin_amdgcn_ds_bpermute(addrA, d11);
      int f2a = __builtin_amdgcn_ds_bpermute(addrB, d00);
      int f2b = __builtin_amdgcn_ds_bpermute(addrB, d10);
      int f3a = __builtin_amdgcn_ds_bpermute(addrB, d01);
      int f3b = __builtin_amdgcn_ds_bpermute(addrB, d11);
      union { short8 s; int i[4]; } pf;
      pf.i[0] = loquad ? f0a : f0b;
      pf.i[1] = loquad ? f1a : f1b;
      pf.i[2] = loquad ? f2a : f2b;
      pf.i[3] = loquad ? f3a : f3b;

      oacc[t][0] = mfma16(vf0, pf.s, oacc[t][0]);
      oacc[t][1] = mfma16(vf1, pf.s, oacc[t][1]);
      oacc[t][2] = mfma16(vf2, pf.s, oacc[t][2]);
      oacc[t][3] = mfma16(vf3, pf.s, oacc[t][3]);
    }
  }

#pragma unroll
  for (int t = 0; t < 2; ++t) {
    L[t] += __shfl_xor(L[t], 16);
    L[t] += __shfl_xor(L[t], 32);
  }

  __shared__ float lbuf[4][2][16];
  __shared__ uint2 obuf[4][2][4][64];

  if (lane < 16) {
    lbuf[wave][0][lane] = L[0];
    lbuf[wave][1][lane] = L[1];
  }
#pragma unroll
  for (int t = 0; t < 2; ++t)
#pragma unroll
    for (int dt = 0; dt < 4; ++dt) {
      uint2 pk;
      pk.x = pk2bf(oacc[t][dt][0], oacc[t][dt][1]);
      pk.y = pk2bf(oacc[t][dt][2], oacc[t][dt][3]);
      obuf[wave][t][dt][lane] = pk;
    }
  __syncthreads();

#pragma unroll
  for (int pp = 0; pp < 2; ++pp) {
    int pi = wave * 2 + pp;
    int t = pi >> 2, dt = pi & 3;
    f32x4 sum = (f32x4){0.f, 0.f, 0.f, 0.f};
#pragma unroll
    for (int w = 0; w < 4; ++w) {
      uint2 pk = obuf[w][t][dt][lane];
      sum[0] += bf2f((unsigned short)(pk.x & 0xffff));
      sum[1] += bf2f((unsigned short)(pk.x >> 16));
      sum[2] += bf2f((unsigned short)(pk.y & 0xffff));
      sum[3] += bf2f((unsigned short)(pk.y >> 16));
    }
    float lstar = lbuf[0][t][l16] + lbuf[1][t][l16] + lbuf[2][t][l16] + lbuf[3][t][l16];
    float rinv = 1.0f / lstar;
    uint2 res;
    res.x = pk2bf(sum[0] * rinv, sum[1] * rinv);
    res.y = pk2bf(sum[2] * rinv, sum[3] * rinv);
    unsigned short* crow = ctx + (size_t)(b * SEQ + qbase + t * 16 + l16) * H
                           + h * DH + dt * 16 + quad * 4;
    *(uint2*)crow = res;
  }
}

// ---------------- launch ----------------
extern "C" void kernel_launch(void* const* d_in, const int* in_sizes, int n_in,
                              void* d_out, int out_size, void* d_ws, size_t ws_size,
                              hipStream_t stream) {
  const float* latent = (const float*)d_in[0];
  const float* ln1_w = (const float*)d_in[1];
  const float* ln1_b = (const float*)d_in[2];
  const float* Wq = (const float*)d_in[3];
  const float* bq = (const float*)d_in[4];
  const float* Wk = (const float*)d_in[5];
  const float* bk = (const float*)d_in[6];
  const float* Wv = (const float*)d_in[7];
  const float* bv = (const float*)d_in[8];
  const float* Wo = (const float*)d_in[9];
  const float* bo = (const float*)d_in[10];
  const float* ln2_w = (const float*)d_in[11];
  const float* ln2_b = (const float*)d_in[12];
  const float* W1 = (const float*)d_in[13];
  const float* b1 = (const float*)d_in[14];
  const float* W2 = (const float*)d_in[15];
  const float* b2 = (const float*)d_in[16];
  float* out = (float*)d_out;

  char* ws = (char*)d_ws;
  unsigned short* WqkvT = (unsigned short*)ws; ws += (size_t)2304 * 768 * 2;
  unsigned short* WoT   = (unsigned short*)ws; ws += (size_t)768 * 768 * 2;
  unsigned short* W1T   = (unsigned short*)ws; ws += (size_t)3072 * 768 * 2;
  unsigned short* W2T   = (unsigned short*)ws; ws += (size_t)768 * 3072 * 2;
  unsigned short* nx    = (unsigned short*)ws; ws += (size_t)MTOK * H * 2;
  unsigned short* nx2   = (unsigned short*)ws; ws += (size_t)MTOK * H * 2;
  unsigned short* qb    = (unsigned short*)ws; ws += (size_t)MTOK * H * 2;
  unsigned short* kb    = (unsigned short*)ws; ws += (size_t)MTOK * H * 2;
  unsigned short* vTb   = (unsigned short*)ws; ws += (size_t)MTOK * H * 2;
  unsigned short* ctx   = (unsigned short*)ws; ws += (size_t)MTOK * H * 2;
  unsigned short* hbuf  = (unsigned short*)ws; ws += (size_t)MTOK * FF * 2;
  float* x1             = (float*)ws;          ws += (size_t)MTOK * H * 4;

  // weight transposes + LN1, one launch
  prep_kernel<<<6912 + MTOK, 256, 0, stream>>>(
      Wq, Wk, Wv, Wo, W1, W2, WqkvT, WoT, W1T, W2T,
      latent, ln1_w, ln1_b, nx);

  // QKV projection (fused, N=2304), 128x128 tiles; K/V written in K'/V' layouts
  gemm128<MODE_QKV><<<32 * 18, 256, 0, stream>>>(
      nx, WqkvT, MTOK, 2304, 768, bq, bk, bv,
      qb, kb, vTb, nullptr);

  // attention (flash v9, dense loads)
  flash_attn_kernel<<<24 * 64, 256, 0, stream>>>(qb, kb, vTb, ctx);

  // output projection + residual -> x1 (fp32), 64x64 tiles BK=128
  gemm64r<<<64 * 12, 256, 0, stream>>>(
      ctx, WoT, MTOK, 768, 768, bo, latent, x1);

  // LN2
  ln_kernel<<<MTOK, 256, 0, stream>>>(x1, ln2_w, ln2_b, nx2);

  // FFN up + GELU -> hbuf (bf16), 128x128 tiles
  gemm128<MODE_GELU><<<32 * 24, 256, 0, stream>>>(
      nx2, W1T, MTOK, 3072, 768, b1, nullptr, nullptr,
      nullptr, nullptr, nullptr, hbuf);

  // FFN down + residual -> d_out (fp32), 64x64 tiles BK=128
  gemm64r<<<64 * 12, 256, 0, stream>>>(
      hbuf, W2T, MTOK, 768, 3072, b2, x1, out);
}